// Round 9
// baseline (145.483 us; speedup 1.0000x reference)
//
#include <hip/hip_runtime.h>

// ---------------- problem constants ----------------
#define BATCH 2
#define NQ    4096
#define MK    4096
#define DD    256
#define ODIM  512
#define SDIM  512
#define NROWS (BATCH * NQ)          // 8192
#define BM    64                    // q rows per flash block
#define BK    64                    // keys per kt iter
#define MSPLIT 4
#define MCHUNK (MK / MSPLIT)        // 1024
#define NKT    (MCHUNK / BK)        // 16
#define XSPLIT (BATCH * NQ * DD)    // elements per X partial split

// chunk counts (1 chunk = 8 shorts = 16B)
#define NCH_V (NROWS * DD / 8)      // 262144
#define NCH_W (ODIM * SDIM / 8)     // 32768
#define RN_BLOCKS 4096              // row-path blocks (16384 rows / 4 per block)

typedef short bf16x8 __attribute__((ext_vector_type(8)));
typedef float f32x16 __attribute__((ext_vector_type(16)));

__device__ __forceinline__ float bf2f(unsigned short h) {
    unsigned int u = ((unsigned int)h) << 16;
    float f;
    __builtin_memcpy(&f, &u, 4);
    return f;
}
__device__ __forceinline__ unsigned short f2bf(float f) {
    unsigned int u;
    __builtin_memcpy(&u, &f, 4);
    u = (u + 0x7FFFu + ((u >> 16) & 1u)) >> 16;   // RNE
    return (unsigned short)u;
}
union frag_cast { uint4 u; bf16x8 b; unsigned short h[8]; };
__device__ __forceinline__ bf16x8 ldg_frag(const unsigned short* p) {
    frag_cast c;
    c.u = *(const uint4*)p;
    return c.b;
}
// async global -> LDS, 16B per lane (global_load_lds_dwordx4)
__device__ __forceinline__ void load_lds16(const unsigned short* g, unsigned short* l) {
    __builtin_amdgcn_global_load_lds(
        (const __attribute__((address_space(1))) void*)g,
        (__attribute__((address_space(3))) void*)l, 16, 0, 0);
}

// ---------------- kernel 1: prep ----------------------------------------------
// blocks [0, RN_BLOCKS): wave-per-row norm+swizzle.
//   em1 rows -> e1sw RAW (GEMM needs raw) + rn[row] = rsqrt(max(||x||^2,eps))
//   em2 rows -> ksw PRE-NORMALIZED (flash needs k-hat only)
// blocks [RN_BLOCKS, ...): chunk path: vsw (raw em2, dim-frag), wsw (W row-frag).
__global__ void prep_kernel(const float* em1, const float* em2, const float* W,
                            float* rn, unsigned short* e1sw, unsigned short* ksw,
                            unsigned short* vsw, unsigned short* wsw) {
    int bid = blockIdx.x;
    int tid = threadIdx.x;
    if (bid < RN_BLOCKS) {
        int row  = bid * 4 + (tid >> 6);    // 0..16383
        int lane = tid & 63;
        bool is_q = row < NROWS;
        int r = is_q ? row : row - NROWS;
        const float* src = (is_q ? em1 : em2) + (size_t)r * DD;
        float4 v = *(const float4*)(src + lane * 4);
        float ss = v.x * v.x + v.y * v.y + v.z * v.z + v.w * v.w;
#pragma unroll
        for (int off = 1; off < 64; off <<= 1) ss += __shfl_xor(ss, off, 64);
        float rs = rsqrtf(fmaxf(ss, 1e-6f));
        float scale = is_q ? 1.0f : rs;
        if (is_q && lane == 0) rn[r] = rs;
        unsigned short* dst = is_q ? e1sw : ksw;
        int g = r >> 5, r31 = r & 31;
        int k = lane * 4;
        ushort4 o;
        o.x = f2bf(v.x * scale); o.y = f2bf(v.y * scale);
        o.z = f2bf(v.z * scale); o.w = f2bf(v.w * scale);
        *(ushort4*)(dst + ((size_t)g * 1024 + (k >> 3) * 32 + r31) * 8 + (k & 7)) = o;
        return;
    }
    int cg = (bid - RN_BLOCKS) * 256 + tid;
    if (cg < NCH_V) {
        int b   = cg >> 17;
        int r   = cg & 131071;
        int dg  = r >> 14;
        int rr  = r & 16383;
        int oct = rr >> 5;
        int d31 = rr & 31;
        const float* sp = em2 + (size_t)(b * MK + oct * 8) * DD + dg * 32 + d31;
        ushort4 o1, o2;
        o1.x = f2bf(sp[0 * DD]); o1.y = f2bf(sp[1 * DD]);
        o1.z = f2bf(sp[2 * DD]); o1.w = f2bf(sp[3 * DD]);
        o2.x = f2bf(sp[4 * DD]); o2.y = f2bf(sp[5 * DD]);
        o2.z = f2bf(sp[6 * DD]); o2.w = f2bf(sp[7 * DD]);
        *(ushort4*)(vsw + (size_t)cg * 8)     = o1;
        *(ushort4*)(vsw + (size_t)cg * 8 + 4) = o2;
    } else {
        int c0 = cg - NCH_V;
        if (c0 >= NCH_W) return;
        int g = c0 >> 11, c = c0 & 2047;
        int c31 = c & 31;
        int k0  = (c >> 5) * 8;
        const float* sp = W + (size_t)(g * 32 + c31) * SDIM + k0;
        float4 a = *(const float4*)sp;
        float4 b = *(const float4*)(sp + 4);
        ushort4 o1, o2;
        o1.x = f2bf(a.x); o1.y = f2bf(a.y); o1.z = f2bf(a.z); o1.w = f2bf(a.w);
        o2.x = f2bf(b.x); o2.y = f2bf(b.y); o2.z = f2bf(b.z); o2.w = f2bf(b.w);
        *(ushort4*)(wsw + (size_t)c0 * 8)     = o1;
        *(ushort4*)(wsw + (size_t)c0 * 8 + 4) = o2;
    }
}

// ---------------- kernel 2: flash attention, m97-style LDS staging -----------
// (R5 structure verbatim; ksw pre-normalized so only rq scaling remains.)
// grid = 512 (mchunk = bid>>7), 256 threads = 4 waves.
__global__ __launch_bounds__(256, 2)
void flash_kernel(const unsigned short* e1sw, const unsigned short* ksw,
                  const unsigned short* vsw, const float* rn,
                  unsigned short* Xp, float* lbuf) {
    __shared__ unsigned short Ks[16384];   // 64 keys x 256 dims, frag order
    __shared__ unsigned short Vs[16384];   // 256 dims x 64 keys, frag order
    __shared__ unsigned short Ps[BM * 72];
    __shared__ float ls[2][BM];
    int tid = threadIdx.x, lane = tid & 63, w = tid >> 6;
    int l31 = lane & 31, lhalf = lane >> 5;
    int wr = w & 1, wc = w >> 1;
    int bid    = blockIdx.x;
    int mchunk = bid >> 7;
    int rowblk = bid & 127;
    int batch  = rowblk >> 6;
    int r0     = rowblk * BM;

    // Q A-frags (raw em1), register-resident for the whole block sweep
    const unsigned short* qbase =
        e1sw + (size_t)(rowblk * 2 + wr) * 8192 + lhalf * 256 + l31 * 8;
    bf16x8 qf[16];
#pragma unroll
    for (int s = 0; s < 16; s++) qf[s] = ldg_frag(qbase + s * 512);

    float rqv[16];
#pragma unroll
    for (int i = 0; i < 16; i++) {
        int m = (i & 3) + 8 * (i >> 2) + 4 * lhalf;
        rqv[i] = rn[r0 + wr * 32 + m];
    }

    const unsigned short* kchunk = ksw + (size_t)(batch * 128 + mchunk * 32) * 8192;
    const unsigned short* vbase  = vsw + (size_t)batch * 1048576 +
                                   (size_t)(mchunk * 128) * 256;

    f32x16 xacc[4];
#pragma unroll
    for (int t = 0; t < 4; t++)
#pragma unroll
        for (int i = 0; i < 16; i++) xacc[t][i] = 0.f;
    float lpart[16];
#pragma unroll
    for (int i = 0; i < 16; i++) lpart[i] = 0.f;

    for (int kt = 0; kt < NKT; kt++) {
        __syncthreads();   // prior PV reads of Ks/Vs complete
        {
            const unsigned short* ksrc = kchunk + (size_t)kt * 16384;
#pragma unroll
            for (int it = 0; it < 8; it++)
                load_lds16(ksrc + it * 2048 + tid * 8, &Ks[it * 2048 + tid * 8]);
            const unsigned short* vsrc = vbase + (size_t)(kt * 8) * 256;
#pragma unroll
            for (int dg = 0; dg < 8; dg++)
                load_lds16(vsrc + (size_t)dg * 131072 + tid * 8, &Vs[dg * 2048 + tid * 8]);
        }
        __syncthreads();   // staging visible
        // ---- QK^T: 32x32 over D=256, two independent acc chains ----
        f32x16 sA, sB;
#pragma unroll
        for (int i = 0; i < 16; i++) { sA[i] = 0.f; sB[i] = 0.f; }
        const unsigned short* kb = &Ks[wc * 8192 + lhalf * 256 + l31 * 8];
#pragma unroll
        for (int s = 0; s < 16; s += 2) {
            bf16x8 b0 = ldg_frag(kb + s * 512);
            bf16x8 b1 = ldg_frag(kb + (s + 1) * 512);
            sA = __builtin_amdgcn_mfma_f32_32x32x16_bf16(qf[s],     b0, sA, 0, 0, 0);
            sB = __builtin_amdgcn_mfma_f32_32x32x16_bf16(qf[s + 1], b1, sB, 0, 0, 0);
        }
        // ---- P = exp(s*rq - 1) (k pre-normalized; cosine max = 1) ----
#pragma unroll
        for (int i = 0; i < 16; i++) {
            float p = __expf((sA[i] + sB[i]) * rqv[i] - 1.0f);
            unsigned short pb = f2bf(p);
            lpart[i] += bf2f(pb);
            int m = wr * 32 + (i & 3) + 8 * (i >> 2) + 4 * lhalf;
            Ps[m * 72 + wc * 32 + l31] = pb;
        }
        __syncthreads();   // P complete
        // ---- PV: rows wr*32, dims wc*128; A from Ps, B from Vs ----
#pragma unroll
        for (int ks = 0; ks < 4; ks++) {
            frag_cast ac;
            ac.u = *(const uint4*)&Ps[(wr * 32 + l31) * 72 + ks * 16 + lhalf * 8];
#pragma unroll
            for (int nt = 0; nt < 4; nt++) {
                bf16x8 bf = ldg_frag(&Vs[((wc * 4 + nt) * 8 + ks * 2 + lhalf) * 256 + l31 * 8]);
                xacc[nt] = __builtin_amdgcn_mfma_f32_32x32x16_bf16(ac.b, bf, xacc[nt], 0, 0, 0);
            }
        }
    }

    // ---- l: per-row sums -> lbuf[split] ----
#pragma unroll
    for (int i = 0; i < 16; i++) {
        float v = lpart[i];
#pragma unroll
        for (int off = 1; off < 32; off <<= 1) v += __shfl_xor(v, off, 64);
        if (l31 == 0) {
            int m = wr * 32 + (i & 3) + 8 * (i >> 2) + 4 * lhalf;
            ls[wc][m] = v;
        }
    }
    __syncthreads();
    if (tid < BM)
        lbuf[(size_t)mchunk * NROWS + r0 + tid] = ls[0][tid] + ls[1][tid];

    // ---- store X partial in row-frag order (bf16, no atomics) ----
    unsigned short* xout = Xp + (size_t)mchunk * XSPLIT +
                           (size_t)(rowblk * 2 + wr) * 8192;
#pragma unroll
    for (int nt = 0; nt < 4; nt++) {
        int dcol = wc * 128 + nt * 32 + l31;
        int cbase = (dcol >> 3) * 256 + (dcol & 7);
#pragma unroll
        for (int i = 0; i < 16; i++) {
            int m = (i & 3) + 8 * (i >> 2) + 4 * lhalf;
            xout[cbase + m * 8] = f2bf(xacc[nt][i]);
        }
    }
}

// ---------------- kernel 3: fused reduce + GEMM ------------------------------
// grid = 256 blocks (one per 32-row group). Phase 1: dequant this group's
// 4 Xp splits ONCE into LDS xn (frag order). Phase 2: GEMM over all 512 cols
// (wave = 128 cols, 4 independent acc chains). h = relu([em1, xn] @ W^T + b).
__global__ __launch_bounds__(256, 2)
void final_gemm(const unsigned short* e1sw, const unsigned short* Xp,
                const float* lbuf, const unsigned short* wsw, const float* bias,
                float* out) {
    __shared__ unsigned short xn[8192];   // 32 rows x 256 dims, frag order
    __shared__ float lrinv[32];
    int tid = threadIdx.x, lane = tid & 63, w = tid >> 6;
    int l31 = lane & 31, lhalf = lane >> 5;
    int rg = blockIdx.x;                   // 32-row group, 0..255

    if (tid < 32) {
        int row = rg * 32 + tid;
        float l = lbuf[row] + lbuf[NROWS + row] +
                  lbuf[2 * NROWS + row] + lbuf[3 * NROWS + row];
        lrinv[tid] = 1.0f / l;
    }
    __syncthreads();

    // phase 1: xn = (sum of splits) / l
    const unsigned short* xb = Xp + (size_t)rg * 8192;
#pragma unroll
    for (int it = 0; it < 4; it++) {
        int c = it * 256 + tid;            // chunk 0..1023 (row = c&31)
        const unsigned short* p = xb + c * 8;
        frag_cast p0, p1, p2, p3, u;
        p0.u = *(const uint4*)p;
        p1.u = *(const uint4*)(p + (size_t)XSPLIT);
        p2.u = *(const uint4*)(p + 2 * (size_t)XSPLIT);
        p3.u = *(const uint4*)(p + 3 * (size_t)XSPLIT);
        float rinv = lrinv[c & 31];
#pragma unroll
        for (int j = 0; j < 8; j++) {
            float f = bf2f(p0.h[j]) + bf2f(p1.h[j]) + bf2f(p2.h[j]) + bf2f(p3.h[j]);
            u.h[j] = f2bf(f * rinv);
        }
        *(uint4*)&xn[c * 8] = u.u;
    }
    __syncthreads();

    // phase 2: GEMM. wave w: cols [w*128, w*128+128) as 4 tiles of 32.
    f32x16 acc[4];
#pragma unroll
    for (int t = 0; t < 4; t++)
#pragma unroll
        for (int i = 0; i < 16; i++) acc[t][i] = 0.f;

    const unsigned short* abase = e1sw + (size_t)rg * 8192 + lhalf * 256 + l31 * 8;
    const unsigned short* bbase = wsw + lhalf * 256 + l31 * 8;

    for (int kk = 0; kk < 32; kk++) {
        bf16x8 afr = (kk < 16)
            ? ldg_frag(abase + kk * 512)
            : ldg_frag(&xn[(kk - 16) * 512 + lhalf * 256 + l31 * 8]);
#pragma unroll
        for (int nt = 0; nt < 4; nt++) {
            bf16x8 bfr = ldg_frag(bbase + (size_t)(w * 4 + nt) * 16384 + kk * 512);
            acc[nt] = __builtin_amdgcn_mfma_f32_32x32x16_bf16(afr, bfr, acc[nt], 0, 0, 0);
        }
    }

#pragma unroll
    for (int nt = 0; nt < 4; nt++) {
        int col = w * 128 + nt * 32 + l31;
        float bb = bias[col];
#pragma unroll
        for (int i = 0; i < 16; i++) {
            int row = rg * 32 + (i & 3) + 8 * (i >> 2) + 4 * lhalf;
            float v = acc[nt][i] + bb;
            v = v > 0.f ? v : 0.f;
            out[(size_t)row * ODIM + col] = v;
        }
    }
}

// ---------------- launch ----------------
extern "C" void kernel_launch(void* const* d_in, const int* in_sizes, int n_in,
                              void* d_out, int out_size, void* d_ws, size_t ws_size,
                              hipStream_t stream) {
    const float* em1  = (const float*)d_in[0];
    const float* em2  = (const float*)d_in[1];
    const float* W    = (const float*)d_in[2];
    const float* bias = (const float*)d_in[3];
    float* out = (float*)d_out;

    char* ws = (char*)d_ws;
    unsigned short* e1sw = (unsigned short*)ws;                     // 4 MB (raw em1)
    unsigned short* ksw  = e1sw + (size_t)NROWS * DD;               // 4 MB (k-hat)
    unsigned short* vsw  = ksw  + (size_t)NROWS * DD;               // 4 MB (raw em2, dim-frag)
    unsigned short* wsw  = vsw  + (size_t)BATCH * DD * MK;          // 0.5 MB
    unsigned short* Xp   = wsw  + (size_t)ODIM * SDIM;              // 16 MB (4 splits)
    float* lbuf = (float*)(Xp + 4 * (size_t)XSPLIT);                // 128 KB
    float* rn   = lbuf + 4 * (size_t)NROWS;                         // 32 KB (em1 norms)

    const int chunk_blocks = (NCH_V + NCH_W + 255) / 256;           // 1152
    prep_kernel<<<RN_BLOCKS + chunk_blocks, 256, 0, stream>>>(
        em1, em2, W, rn, e1sw, ksw, vsw, wsw);
    flash_kernel<<<(NROWS / BM) * MSPLIT, 256, 0, stream>>>(e1sw, ksw, vsw, rn, Xp, lbuf);
    final_gemm<<<NROWS / 32, 256, 0, stream>>>(e1sw, Xp, lbuf, wsw, bias, out);
}

// Round 10
// 136.189 us; speedup vs baseline: 1.0682x; 1.0682x over previous
//
#include <hip/hip_runtime.h>

// ---------------- problem constants ----------------
#define BATCH 2
#define NQ    4096
#define MK    4096
#define DD    256
#define ODIM  512
#define SDIM  512
#define NROWS (BATCH * NQ)          // 8192
#define BM    64                    // q rows per flash block
#define BK    64                    // keys per kt iter
#define MSPLIT 4
#define MCHUNK (MK / MSPLIT)        // 1024
#define NKT    (MCHUNK / BK)        // 16
#define XSPLIT (BATCH * NQ * DD)    // elements per X partial split

// chunk counts (1 chunk = 8 shorts = 16B)
#define NCH_V (NROWS * DD / 8)      // 262144
#define NCH_W (ODIM * SDIM / 8)     // 32768
#define RN_BLOCKS 4096              // row-path blocks (16384 rows / 4 per block)

typedef short bf16x8 __attribute__((ext_vector_type(8)));
typedef float f32x16 __attribute__((ext_vector_type(16)));

__device__ __forceinline__ float bf2f(unsigned short h) {
    unsigned int u = ((unsigned int)h) << 16;
    float f;
    __builtin_memcpy(&f, &u, 4);
    return f;
}
__device__ __forceinline__ unsigned short f2bf(float f) {
    unsigned int u;
    __builtin_memcpy(&u, &f, 4);
    u = (u + 0x7FFFu + ((u >> 16) & 1u)) >> 16;   // RNE
    return (unsigned short)u;
}
union frag_cast { uint4 u; bf16x8 b; unsigned short h[8]; };
__device__ __forceinline__ bf16x8 ldg_frag(const unsigned short* p) {
    frag_cast c;
    c.u = *(const uint4*)p;
    return c.b;
}
// async global -> LDS, 16B per lane (global_load_lds_dwordx4)
__device__ __forceinline__ void load_lds16(const unsigned short* g, unsigned short* l) {
    __builtin_amdgcn_global_load_lds(
        (const __attribute__((address_space(1))) void*)g,
        (__attribute__((address_space(3))) void*)l, 16, 0, 0);
}

// ---------------- kernel 1: prep (R9 version) ---------------------------------
// blocks [0, RN_BLOCKS): wave-per-row norm+swizzle.
//   em1 rows -> e1sw RAW (GEMM needs raw) + rn[row] = rsqrt(max(||x||^2,eps))
//   em2 rows -> ksw PRE-NORMALIZED (flash needs k-hat only)
// blocks [RN_BLOCKS, ...): chunk path: vsw (raw em2, dim-frag), wsw (W row-frag).
__global__ void prep_kernel(const float* em1, const float* em2, const float* W,
                            float* rn, unsigned short* e1sw, unsigned short* ksw,
                            unsigned short* vsw, unsigned short* wsw) {
    int bid = blockIdx.x;
    int tid = threadIdx.x;
    if (bid < RN_BLOCKS) {
        int row  = bid * 4 + (tid >> 6);    // 0..16383
        int lane = tid & 63;
        bool is_q = row < NROWS;
        int r = is_q ? row : row - NROWS;
        const float* src = (is_q ? em1 : em2) + (size_t)r * DD;
        float4 v = *(const float4*)(src + lane * 4);
        float ss = v.x * v.x + v.y * v.y + v.z * v.z + v.w * v.w;
#pragma unroll
        for (int off = 1; off < 64; off <<= 1) ss += __shfl_xor(ss, off, 64);
        float rs = rsqrtf(fmaxf(ss, 1e-6f));
        float scale = is_q ? 1.0f : rs;
        if (is_q && lane == 0) rn[r] = rs;
        unsigned short* dst = is_q ? e1sw : ksw;
        int g = r >> 5, r31 = r & 31;
        int k = lane * 4;
        ushort4 o;
        o.x = f2bf(v.x * scale); o.y = f2bf(v.y * scale);
        o.z = f2bf(v.z * scale); o.w = f2bf(v.w * scale);
        *(ushort4*)(dst + ((size_t)g * 1024 + (k >> 3) * 32 + r31) * 8 + (k & 7)) = o;
        return;
    }
    int cg = (bid - RN_BLOCKS) * 256 + tid;
    if (cg < NCH_V) {
        int b   = cg >> 17;
        int r   = cg & 131071;
        int dg  = r >> 14;
        int rr  = r & 16383;
        int oct = rr >> 5;
        int d31 = rr & 31;
        const float* sp = em2 + (size_t)(b * MK + oct * 8) * DD + dg * 32 + d31;
        ushort4 o1, o2;
        o1.x = f2bf(sp[0 * DD]); o1.y = f2bf(sp[1 * DD]);
        o1.z = f2bf(sp[2 * DD]); o1.w = f2bf(sp[3 * DD]);
        o2.x = f2bf(sp[4 * DD]); o2.y = f2bf(sp[5 * DD]);
        o2.z = f2bf(sp[6 * DD]); o2.w = f2bf(sp[7 * DD]);
        *(ushort4*)(vsw + (size_t)cg * 8)     = o1;
        *(ushort4*)(vsw + (size_t)cg * 8 + 4) = o2;
    } else {
        int c0 = cg - NCH_V;
        if (c0 >= NCH_W) return;
        int g = c0 >> 11, c = c0 & 2047;
        int c31 = c & 31;
        int k0  = (c >> 5) * 8;
        const float* sp = W + (size_t)(g * 32 + c31) * SDIM + k0;
        float4 a = *(const float4*)sp;
        float4 b = *(const float4*)(sp + 4);
        ushort4 o1, o2;
        o1.x = f2bf(a.x); o1.y = f2bf(a.y); o1.z = f2bf(a.z); o1.w = f2bf(a.w);
        o2.x = f2bf(b.x); o2.y = f2bf(b.y); o2.z = f2bf(b.z); o2.w = f2bf(b.w);
        *(ushort4*)(wsw + (size_t)c0 * 8)     = o1;
        *(ushort4*)(wsw + (size_t)c0 * 8 + 4) = o2;
    }
}

// ---------------- kernel 2: flash attention (R9 version — best: 53.2 us) -----
// m97-style LDS staging; ksw pre-normalized so only rq scaling remains.
// grid = 512 (mchunk = bid>>7), 256 threads = 4 waves.
__global__ __launch_bounds__(256, 2)
void flash_kernel(const unsigned short* e1sw, const unsigned short* ksw,
                  const unsigned short* vsw, const float* rn,
                  unsigned short* Xp, float* lbuf) {
    __shared__ unsigned short Ks[16384];   // 64 keys x 256 dims, frag order
    __shared__ unsigned short Vs[16384];   // 256 dims x 64 keys, frag order
    __shared__ unsigned short Ps[BM * 72];
    __shared__ float ls[2][BM];
    int tid = threadIdx.x, lane = tid & 63, w = tid >> 6;
    int l31 = lane & 31, lhalf = lane >> 5;
    int wr = w & 1, wc = w >> 1;
    int bid    = blockIdx.x;
    int mchunk = bid >> 7;
    int rowblk = bid & 127;
    int batch  = rowblk >> 6;
    int r0     = rowblk * BM;

    // Q A-frags (raw em1), register-resident for the whole block sweep
    const unsigned short* qbase =
        e1sw + (size_t)(rowblk * 2 + wr) * 8192 + lhalf * 256 + l31 * 8;
    bf16x8 qf[16];
#pragma unroll
    for (int s = 0; s < 16; s++) qf[s] = ldg_frag(qbase + s * 512);

    float rqv[16];
#pragma unroll
    for (int i = 0; i < 16; i++) {
        int m = (i & 3) + 8 * (i >> 2) + 4 * lhalf;
        rqv[i] = rn[r0 + wr * 32 + m];
    }

    const unsigned short* kchunk = ksw + (size_t)(batch * 128 + mchunk * 32) * 8192;
    const unsigned short* vbase  = vsw + (size_t)batch * 1048576 +
                                   (size_t)(mchunk * 128) * 256;

    f32x16 xacc[4];
#pragma unroll
    for (int t = 0; t < 4; t++)
#pragma unroll
        for (int i = 0; i < 16; i++) xacc[t][i] = 0.f;
    float lpart[16];
#pragma unroll
    for (int i = 0; i < 16; i++) lpart[i] = 0.f;

    for (int kt = 0; kt < NKT; kt++) {
        __syncthreads();   // prior PV reads of Ks/Vs complete
        {
            const unsigned short* ksrc = kchunk + (size_t)kt * 16384;
#pragma unroll
            for (int it = 0; it < 8; it++)
                load_lds16(ksrc + it * 2048 + tid * 8, &Ks[it * 2048 + tid * 8]);
            const unsigned short* vsrc = vbase + (size_t)(kt * 8) * 256;
#pragma unroll
            for (int dg = 0; dg < 8; dg++)
                load_lds16(vsrc + (size_t)dg * 131072 + tid * 8, &Vs[dg * 2048 + tid * 8]);
        }
        __syncthreads();   // staging visible
        // ---- QK^T: 32x32 over D=256, two independent acc chains ----
        f32x16 sA, sB;
#pragma unroll
        for (int i = 0; i < 16; i++) { sA[i] = 0.f; sB[i] = 0.f; }
        const unsigned short* kb = &Ks[wc * 8192 + lhalf * 256 + l31 * 8];
#pragma unroll
        for (int s = 0; s < 16; s += 2) {
            bf16x8 b0 = ldg_frag(kb + s * 512);
            bf16x8 b1 = ldg_frag(kb + (s + 1) * 512);
            sA = __builtin_amdgcn_mfma_f32_32x32x16_bf16(qf[s],     b0, sA, 0, 0, 0);
            sB = __builtin_amdgcn_mfma_f32_32x32x16_bf16(qf[s + 1], b1, sB, 0, 0, 0);
        }
        // ---- P = exp(s*rq - 1) (k pre-normalized; cosine max = 1) ----
#pragma unroll
        for (int i = 0; i < 16; i++) {
            float p = __expf((sA[i] + sB[i]) * rqv[i] - 1.0f);
            unsigned short pb = f2bf(p);
            lpart[i] += bf2f(pb);
            int m = wr * 32 + (i & 3) + 8 * (i >> 2) + 4 * lhalf;
            Ps[m * 72 + wc * 32 + l31] = pb;
        }
        __syncthreads();   // P complete
        // ---- PV: rows wr*32, dims wc*128; A from Ps, B from Vs ----
#pragma unroll
        for (int ks = 0; ks < 4; ks++) {
            frag_cast ac;
            ac.u = *(const uint4*)&Ps[(wr * 32 + l31) * 72 + ks * 16 + lhalf * 8];
#pragma unroll
            for (int nt = 0; nt < 4; nt++) {
                bf16x8 bf = ldg_frag(&Vs[((wc * 4 + nt) * 8 + ks * 2 + lhalf) * 256 + l31 * 8]);
                xacc[nt] = __builtin_amdgcn_mfma_f32_32x32x16_bf16(ac.b, bf, xacc[nt], 0, 0, 0);
            }
        }
    }

    // ---- l: per-row sums -> lbuf[split] ----
#pragma unroll
    for (int i = 0; i < 16; i++) {
        float v = lpart[i];
#pragma unroll
        for (int off = 1; off < 32; off <<= 1) v += __shfl_xor(v, off, 64);
        if (l31 == 0) {
            int m = wr * 32 + (i & 3) + 8 * (i >> 2) + 4 * lhalf;
            ls[wc][m] = v;
        }
    }
    __syncthreads();
    if (tid < BM)
        lbuf[(size_t)mchunk * NROWS + r0 + tid] = ls[0][tid] + ls[1][tid];

    // ---- store X partial in row-frag order (bf16, no atomics) ----
    unsigned short* xout = Xp + (size_t)mchunk * XSPLIT +
                           (size_t)(rowblk * 2 + wr) * 8192;
#pragma unroll
    for (int nt = 0; nt < 4; nt++) {
        int dcol = wc * 128 + nt * 32 + l31;
        int cbase = (dcol >> 3) * 256 + (dcol & 7);
#pragma unroll
        for (int i = 0; i < 16; i++) {
            int m = (i & 3) + 8 * (i >> 2) + 4 * lhalf;
            xout[cbase + m * 8] = f2bf(xacc[nt][i]);
        }
    }
}

// ---------------- kernel 3: xnsw = (sum of 4 X splits) / (sum l) -------------
__global__ void reduce_kernel(const unsigned short* Xp, const float* lbuf,
                              unsigned short* xnsw) {
    int cg  = blockIdx.x * 256 + threadIdx.x;
    int row = (cg >> 10) * 32 + (cg & 31);
    float l = lbuf[row] + lbuf[NROWS + row] +
              lbuf[2 * NROWS + row] + lbuf[3 * NROWS + row];
    float rinv = 1.0f / l;
    const unsigned short* p = Xp + (size_t)cg * 8;
    frag_cast p0, p1, p2, p3, u;
    p0.u = *(const uint4*)p;
    p1.u = *(const uint4*)(p + (size_t)XSPLIT);
    p2.u = *(const uint4*)(p + 2 * (size_t)XSPLIT);
    p3.u = *(const uint4*)(p + 3 * (size_t)XSPLIT);
#pragma unroll
    for (int j = 0; j < 8; j++) {
        float f = bf2f(p0.h[j]) + bf2f(p1.h[j]) + bf2f(p2.h[j]) + bf2f(p3.h[j]);
        u.h[j] = f2bf(f * rinv);
    }
    *(uint4*)(xnsw + (size_t)cg * 8) = u.u;
}

// ---------------- kernel 4: h = relu([em1, xn] @ W^T + b), f32 out -----------
// (R8 version — 64x64 tiles, grid 1024, rb-major for XCD A-row L2 reuse.)
__global__ __launch_bounds__(256, 4)
void final_gemm(const unsigned short* e1sw, const unsigned short* xnsw,
                const unsigned short* wsw, const float* bias, float* out) {
    int tid = threadIdx.x, lane = tid & 63, w = tid >> 6;
    int l31 = lane & 31, lhalf = lane >> 5;
    int wr = w & 1, wc = w >> 1;
    int bid = blockIdx.x;
    int rb = bid & 127, cb = bid >> 7;     // 128 row-blocks x 8 col-blocks
    int gA = rb * 2 + wr;                  // 32-row group (0..255)
    int gB = cb * 2 + wc;                  // 32-col group (0..15)

    f32x16 acc;
#pragma unroll
    for (int i = 0; i < 16; i++) acc[i] = 0.f;

    const unsigned short* abase = e1sw + (size_t)gA * 8192 + lhalf * 256 + l31 * 8;
    const unsigned short* xbase = xnsw + (size_t)gA * 8192 + lhalf * 256 + l31 * 8;
    const unsigned short* bbase = wsw  + (size_t)gB * 16384 + lhalf * 256 + l31 * 8;

    for (int kk = 0; kk < 32; kk++) {
        bf16x8 afr = (kk < 16) ? ldg_frag(abase + kk * 512)
                               : ldg_frag(xbase + (kk - 16) * 512);
        bf16x8 bfr = ldg_frag(bbase + kk * 512);
        acc = __builtin_amdgcn_mfma_f32_32x32x16_bf16(afr, bfr, acc, 0, 0, 0);
    }

    int col = gB * 32 + l31;
    float bb = bias[col];
#pragma unroll
    for (int i = 0; i < 16; i++) {
        int row = gA * 32 + (i & 3) + 8 * (i >> 2) + 4 * lhalf;
        float v = acc[i] + bb;
        v = v > 0.f ? v : 0.f;
        out[(size_t)row * ODIM + col] = v;
    }
}

// ---------------- launch ----------------
extern "C" void kernel_launch(void* const* d_in, const int* in_sizes, int n_in,
                              void* d_out, int out_size, void* d_ws, size_t ws_size,
                              hipStream_t stream) {
    const float* em1  = (const float*)d_in[0];
    const float* em2  = (const float*)d_in[1];
    const float* W    = (const float*)d_in[2];
    const float* bias = (const float*)d_in[3];
    float* out = (float*)d_out;

    char* ws = (char*)d_ws;
    unsigned short* e1sw = (unsigned short*)ws;                     // 4 MB (raw em1)
    unsigned short* ksw  = e1sw + (size_t)NROWS * DD;               // 4 MB (k-hat)
    unsigned short* vsw  = ksw  + (size_t)NROWS * DD;               // 4 MB (raw em2, dim-frag)
    unsigned short* wsw  = vsw  + (size_t)BATCH * DD * MK;          // 0.5 MB
    unsigned short* Xp   = wsw  + (size_t)ODIM * SDIM;              // 16 MB (4 splits)
    unsigned short* xnsw = Xp   + 4 * (size_t)XSPLIT;               // 4 MB
    float* lbuf = (float*)(xnsw + (size_t)NROWS * DD);              // 128 KB
    float* rn   = lbuf + 4 * (size_t)NROWS;                         // 32 KB (em1 norms)

    const int chunk_blocks = (NCH_V + NCH_W + 255) / 256;           // 1152
    prep_kernel<<<RN_BLOCKS + chunk_blocks, 256, 0, stream>>>(
        em1, em2, W, rn, e1sw, ksw, vsw, wsw);
    flash_kernel<<<(NROWS / BM) * MSPLIT, 256, 0, stream>>>(e1sw, ksw, vsw, rn, Xp, lbuf);
    reduce_kernel<<<NCH_V / 256, 256, 0, stream>>>(Xp, lbuf, xnsw);
    final_gemm<<<(NROWS / 64) * (ODIM / 64), 256, 0, stream>>>(
        e1sw, xnsw, wsw, bias, out);
}